// Round 1
// baseline (219.441 us; speedup 1.0000x reference)
//
#include <hip/hip_runtime.h>

#define L_SEQ 2688
#define DIM   1536
#define NH    12
#define HD    128
#define BLK_TOK 1344   // 3*H*W
#define HW_   448      // H*W
#define W_    28

typedef unsigned short u16;
typedef unsigned int   u32;
typedef __attribute__((ext_vector_type(4))) float f32x4;
typedef __attribute__((ext_vector_type(8))) short s16x8;

__device__ __forceinline__ u16 f2b(float f) {
    u32 u = __builtin_bit_cast(u32, f);
    return (u16)((u + 0x7FFFu + ((u >> 16) & 1u)) >> 16);   // RNE
}
__device__ __forceinline__ float b2f(u16 b) {
    return __builtin_bit_cast(float, (u32)b << 16);
}

// ---------------------------------------------------------------- x -> bf16
__global__ __launch_bounds__(256) void k_cvt_x(const float* __restrict__ x,
                                               u16* __restrict__ xb, int n4) {
    int i = blockIdx.x * 256 + threadIdx.x;
    int stride = gridDim.x * 256;
    for (; i < n4; i += stride) {
        float4 v = ((const float4*)x)[i];
        ushort4 o;
        o.x = f2b(v.x); o.y = f2b(v.y); o.z = f2b(v.z); o.w = f2b(v.w);
        ((ushort4*)xb)[i] = o;
    }
}

// ------------------------------------- W (f32 [K][N]) -> Wt (bf16 [N][K])
__global__ __launch_bounds__(256) void k_trans_w(const float* __restrict__ w0,
                                                 const float* __restrict__ w1,
                                                 const float* __restrict__ w2,
                                                 const float* __restrict__ w3,
                                                 u16* __restrict__ wt_all) {
    const float* w = blockIdx.z == 0 ? w0 : blockIdx.z == 1 ? w1 : blockIdx.z == 2 ? w2 : w3;
    u16* wt = wt_all + (size_t)blockIdx.z * DIM * DIM;
    __shared__ float t[64][65];
    const int k0 = blockIdx.y * 64, n0 = blockIdx.x * 64;
    const int c = threadIdx.x & 63, rg = threadIdx.x >> 6;
#pragma unroll
    for (int it = 0; it < 16; ++it) {
        int r = rg * 16 + it;
        t[r][c] = w[(size_t)(k0 + r) * DIM + n0 + c];
    }
    __syncthreads();
#pragma unroll
    for (int it = 0; it < 16; ++it) {
        int r = rg * 16 + it;
        wt[(size_t)(n0 + r) * DIM + k0 + c] = f2b(t[c][r]);
    }
}

// ------------------------------------------------- GEMM: C = A*Bt^T + bias
// A bf16 [M=2688][K=1536] row-major, Bt bf16 [N][K] row-major.
// 128x128 tile, BK=32, 4 waves (2x2 of 64x64), 16x16x32 bf16 MFMA.
template<int OUTF>
__global__ __launch_bounds__(256, 2) void k_gemm(const u16* __restrict__ A,
                                                 const u16* __restrict__ Bt_all,
                                                 const float* __restrict__ b0,
                                                 const float* __restrict__ b1,
                                                 const float* __restrict__ b2,
                                                 void* __restrict__ out_all) {
    const int z = blockIdx.z;
    const u16* Bt = Bt_all + (size_t)z * DIM * DIM;
    const float* bias = z == 0 ? b0 : z == 1 ? b1 : b2;

    __shared__ u16 lA[128 * 32];
    __shared__ u16 lB[128 * 32];
    const int tid = threadIdx.x, lane = tid & 63, wid = tid >> 6;
    const int wm = wid >> 1, wn = wid & 1;
    const int bm = blockIdx.y, bn = blockIdx.x;
    const int lr = lane & 15, lg = lane >> 4;

    f32x4 acc[4][4] = {};

    for (int kt = 0; kt < DIM / 32; ++kt) {
#pragma unroll
        for (int i = 0; i < 2; ++i) {
            int s = wid * 128 + i * 64 + lane;        // 16B slot id
            int row = s >> 2, c16 = s & 3;            // 4 slots per 32-elem row
            const u16* ga = A + (size_t)(bm * 128 + row) * DIM + kt * 32 + c16 * 8;
            __builtin_amdgcn_global_load_lds(
                (const __attribute__((address_space(1))) u32*)ga,
                (__attribute__((address_space(3))) u32*)&lA[(wid * 128 + i * 64) * 8],
                16, 0, 0);
            const u16* gb = Bt + (size_t)(bn * 128 + row) * DIM + kt * 32 + c16 * 8;
            __builtin_amdgcn_global_load_lds(
                (const __attribute__((address_space(1))) u32*)gb,
                (__attribute__((address_space(3))) u32*)&lB[(wid * 128 + i * 64) * 8],
                16, 0, 0);
        }
        __syncthreads();
        s16x8 af[4], bf[4];
#pragma unroll
        for (int m = 0; m < 4; ++m)
            af[m] = *(const s16x8*)&lA[(wm * 64 + m * 16 + lr) * 32 + lg * 8];
#pragma unroll
        for (int n = 0; n < 4; ++n)
            bf[n] = *(const s16x8*)&lB[(wn * 64 + n * 16 + lr) * 32 + lg * 8];
#pragma unroll
        for (int m = 0; m < 4; ++m)
#pragma unroll
            for (int n = 0; n < 4; ++n)
                acc[m][n] = __builtin_amdgcn_mfma_f32_16x16x32_bf16(af[m], bf[n], acc[m][n], 0, 0, 0);
        __syncthreads();
    }
#pragma unroll
    for (int n = 0; n < 4; ++n) {
        int col = bn * 128 + wn * 64 + n * 16 + lr;
        float bv = bias[col];
#pragma unroll
        for (int m = 0; m < 4; ++m) {
            int row0 = bm * 128 + wm * 64 + m * 16 + lg * 4;
#pragma unroll
            for (int r = 0; r < 4; ++r) {
                float v = acc[m][n][r] + bv;
                if (OUTF)
                    ((float*)out_all)[(size_t)(row0 + r) * DIM + col] = v;
                else
                    ((u16*)out_all)[(size_t)z * L_SEQ * DIM + (size_t)(row0 + r) * DIM + col] = f2b(v);
            }
        }
    }
}

// ------------------------------------ RMSNorm(row of 1536) + RoPE -> [h][i][d]
__global__ __launch_bounds__(256) void k_norm_rope(const u16* __restrict__ pre,
                                                   const float* __restrict__ g,
                                                   const float* __restrict__ freqs,
                                                   u16* __restrict__ outh) {
    const int i = blockIdx.x;
    const int t = threadIdx.x;
    const u32* prow = (const u32*)(pre + (size_t)i * DIM);  // 768 bf16 pairs

    float re[3], im[3];
    float ss = 0.f;
#pragma unroll
    for (int a = 0; a < 3; ++a) {
        u32 p = prow[t + a * 256];
        float x = b2f((u16)(p & 0xFFFFu)), y = b2f((u16)(p >> 16));
        re[a] = x; im[a] = y;
        ss += x * x + y * y;
    }
#pragma unroll
    for (int o = 32; o > 0; o >>= 1) ss += __shfl_down(ss, o, 64);
    __shared__ float sred[4];
    if ((t & 63) == 0) sred[t >> 6] = ss;
    __syncthreads();
    float rms = rsqrtf((sred[0] + sred[1] + sred[2] + sred[3]) * (1.0f / DIM) + 1e-6f);

    const int f = i / HW_;
    const int rem = i - f * HW_;
    const int hp = rem / W_;
    const int wp = rem - hp * W_;
#pragma unroll
    for (int a = 0; a < 3; ++a) {
        int j = t + a * 256;         // pair index in row: head h = j>>6, pj = j&63
        int h = j >> 6, pj = j & 63;
        float2 gg = ((const float2*)g)[j];
        float x = re[a] * rms * gg.x;
        float y = im[a] * rms * gg.y;
        int ridx = pj < 22 ? f : (pj < 43 ? hp : wp);
        float2 cs = ((const float2*)freqs)[ridx * 64 + pj];
        float ore = x * cs.x - y * cs.y;
        float oim = x * cs.y + y * cs.x;
        u32 o = (u32)f2b(ore) | ((u32)f2b(oim) << 16);
        ((u32*)outh)[(size_t)h * (L_SEQ * 64) + (size_t)i * 64 + pj] = o;
    }
}

// ------------------------------------------ v [i][h*128+d] -> vt [h][d][i]
__global__ __launch_bounds__(256) void k_vtrans(const u16* __restrict__ vpre,
                                                u16* __restrict__ vt) {
    const int i0 = blockIdx.x * 64, d0 = blockIdx.y * 64, h = blockIdx.z;
    __shared__ u16 t[64][68];
    const int c = threadIdx.x & 63, rg = threadIdx.x >> 6;
#pragma unroll
    for (int it = 0; it < 16; ++it) {
        int r = rg * 16 + it;
        t[r][c] = vpre[(size_t)(i0 + r) * DIM + h * HD + d0 + c];
    }
    __syncthreads();
#pragma unroll
    for (int it = 0; it < 16; ++it) {
        int r = rg * 16 + it;  // d index
        vt[(size_t)h * (HD * L_SEQ) + (size_t)(d0 + r) * L_SEQ + i0 + c] = t[c][r];
    }
}

// ----------------------------------------------------- flash attention
// grid (21, 12). 512 threads = 8 waves; wave owns 16 q-rows. KV tile = 64.
// Block-causal: limits (1344) are multiples of 64 and 16 -> wave-uniform bounds.
__global__ __launch_bounds__(512, 2) void k_attn(const u16* __restrict__ qh,
                                                 const u16* __restrict__ kh,
                                                 const u16* __restrict__ vt,
                                                 u16* __restrict__ ob) {
    const int qt = blockIdx.x, head = blockIdx.y;
    const int tid = threadIdx.x, lane = tid & 63, wid = tid >> 6;
    const int lr = lane & 15, lg = lane >> 4;
    __shared__ u16 lK[64 * 128];   // [j][d], XOR-swizzled
    __shared__ u16 lV[128 * 64];   // [d][j], XOR-swizzled
    __shared__ u16 lP[128 * 64];   // [qrow][j], XOR-swizzled (per-wave private rows)
    const size_t hQ = (size_t)head * ((size_t)L_SEQ * HD);
    const int qrow0 = qt * 128 + wid * 16;

    s16x8 aq[4];
#pragma unroll
    for (int kk = 0; kk < 4; ++kk)
        aq[kk] = *(const s16x8*)&qh[hQ + (size_t)(qrow0 + lr) * HD + kk * 32 + lg * 8];

    f32x4 acc[8] = {};
    float mrun[4], lrun[4];
#pragma unroll
    for (int r = 0; r < 4; ++r) { mrun[r] = -1e30f; lrun[r] = 0.f; }

    const int nt_wave = (qrow0 < BLK_TOK) ? (BLK_TOK / 64) : (L_SEQ / 64);
    const int nt_blk  = (qt * 128 + 127 < BLK_TOK) ? (BLK_TOK / 64) : (L_SEQ / 64);
    const float sc = 0.088388347648318447f;  // 1/sqrt(128)

    for (int t = 0; t < nt_blk; ++t) {
        // stage K tile [64][128] (reg-staged so we can swizzle)
#pragma unroll
        for (int it = 0; it < 2; ++it) {
            int s = tid + it * 512;
            int j = s >> 4, c16 = s & 15;
            s16x8 v = *(const s16x8*)&kh[hQ + (size_t)(t * 64 + j) * HD + c16 * 8];
            int off = j * 256 + ((c16 * 16) ^ ((j & 15) << 4));
            *(s16x8*)((char*)lK + off) = v;
        }
        // stage V^T tile [128][64]
#pragma unroll
        for (int it = 0; it < 2; ++it) {
            int s = tid + it * 512;
            int d = s >> 3, c16 = s & 7;
            s16x8 v = *(const s16x8*)&vt[(size_t)head * ((size_t)HD * L_SEQ) + (size_t)d * L_SEQ + t * 64 + c16 * 8];
            int off = d * 128 + ((c16 * 16) ^ ((d & 7) << 4));
            *(s16x8*)((char*)lV + off) = v;
        }
        __syncthreads();

        if (t < nt_wave) {
            // S = Q K^T : 16 x 64 for this wave
            f32x4 sv[4] = {};
#pragma unroll
            for (int n = 0; n < 4; ++n) {
                int j = n * 16 + lr;
#pragma unroll
                for (int kk = 0; kk < 4; ++kk) {
                    int off = j * 256 + (((kk * 64 + lg * 16)) ^ ((j & 15) << 4));
                    s16x8 bk = *(const s16x8*)((const char*)lK + off);
                    sv[n] = __builtin_amdgcn_mfma_f32_16x16x32_bf16(aq[kk], bk, sv[n], 0, 0, 0);
                }
            }
            // online softmax per q-row (row stats live in 16-lane col groups)
#pragma unroll
            for (int r = 0; r < 4; ++r) {
                float v = fmaxf(fmaxf(sv[0][r], sv[1][r]), fmaxf(sv[2][r], sv[3][r]));
                v = fmaxf(v, __shfl_xor(v, 1, 64));
                v = fmaxf(v, __shfl_xor(v, 2, 64));
                v = fmaxf(v, __shfl_xor(v, 4, 64));
                v = fmaxf(v, __shfl_xor(v, 8, 64));
                float mx = v * sc;
                float mnew = fmaxf(mrun[r], mx);
                float fac = __expf(mrun[r] - mnew);
                mrun[r] = mnew;
                float sum = 0.f;
#pragma unroll
                for (int n = 0; n < 4; ++n) {
                    float p = __expf(sv[n][r] * sc - mnew);
                    sv[n][r] = p;
                    sum += p;
                }
                sum += __shfl_xor(sum, 1, 64);
                sum += __shfl_xor(sum, 2, 64);
                sum += __shfl_xor(sum, 4, 64);
                sum += __shfl_xor(sum, 8, 64);
                lrun[r] = lrun[r] * fac + sum;
#pragma unroll
                for (int nd = 0; nd < 8; ++nd) acc[nd][r] *= fac;
            }
            // P -> LDS (bf16, swizzled); wave-private rows so no barrier needed
#pragma unroll
            for (int n = 0; n < 4; ++n)
#pragma unroll
                for (int r = 0; r < 4; ++r) {
                    int rowl = wid * 16 + lg * 4 + r;
                    int jb = (n * 16 + lr) * 2;
                    *(u16*)((char*)lP + rowl * 128 + (jb ^ ((rowl & 7) << 4))) = f2b(sv[n][r]);
                }
            // O += P V
#pragma unroll
            for (int kk2 = 0; kk2 < 2; ++kk2) {
                int rowl = wid * 16 + lr;
                int jb = kk2 * 64 + lg * 16;
                s16x8 pa = *(const s16x8*)((const char*)lP + rowl * 128 + (jb ^ ((rowl & 7) << 4)));
#pragma unroll
                for (int nd = 0; nd < 8; ++nd) {
                    int d = nd * 16 + lr;
                    s16x8 bv = *(const s16x8*)((const char*)lV + d * 128 + (jb ^ ((d & 7) << 4)));
                    acc[nd] = __builtin_amdgcn_mfma_f32_16x16x32_bf16(pa, bv, acc[nd], 0, 0, 0);
                }
            }
        }
        __syncthreads();
    }
    // normalize + write bf16 [L][DIM]
#pragma unroll
    for (int r = 0; r < 4; ++r) {
        float inv = 1.0f / lrun[r];
        int row = qrow0 + lg * 4 + r;
#pragma unroll
        for (int nd = 0; nd < 8; ++nd) {
            int col = head * HD + nd * 16 + lr;
            ob[(size_t)row * DIM + col] = f2b(acc[nd][r] * inv);
        }
    }
}

// ---------------------------------------------------------------- launcher
extern "C" void kernel_launch(void* const* d_in, const int* in_sizes, int n_in,
                              void* d_out, int out_size, void* d_ws, size_t ws_size,
                              hipStream_t stream) {
    const float* x     = (const float*)d_in[0];
    const float* freqs = (const float*)d_in[3];
    const float* Wq    = (const float*)d_in[4];
    const float* bq    = (const float*)d_in[5];
    const float* Wk    = (const float*)d_in[6];
    const float* bk    = (const float*)d_in[7];
    const float* Wv    = (const float*)d_in[8];
    const float* bv    = (const float*)d_in[9];
    const float* Wo    = (const float*)d_in[10];
    const float* bo    = (const float*)d_in[11];
    const float* gq    = (const float*)d_in[12];
    const float* gk    = (const float*)d_in[13];

    const size_t LD = (size_t)L_SEQ * DIM;   // elements
    u16* wt_all  = (u16*)d_ws;                         // 4 * DIM*DIM bf16
    u16* xb      = wt_all + (size_t)4 * DIM * DIM;     // L*DIM
    u16* pre_all = xb + LD;                            // 3 * L*DIM (q,k,v pre)
    u16* qh      = pre_all + 3 * LD;                   // [h][i][d]
    u16* kh2     = qh + LD;
    u16* vt      = kh2 + LD;
    u16* ob      = vt + LD;                            // attn out bf16 [i][c]

    k_cvt_x<<<2016, 256, 0, stream>>>(x, xb, (int)(LD / 4));
    k_trans_w<<<dim3(24, 24, 4), 256, 0, stream>>>(Wq, Wk, Wv, Wo, wt_all);
    k_gemm<0><<<dim3(12, 21, 3), 256, 0, stream>>>(xb, wt_all, bq, bk, bv, pre_all);
    k_norm_rope<<<L_SEQ, 256, 0, stream>>>(pre_all, gq, freqs, qh);
    k_norm_rope<<<L_SEQ, 256, 0, stream>>>(pre_all + LD, gk, freqs, kh2);
    k_vtrans<<<dim3(42, 2, NH), 256, 0, stream>>>(pre_all + 2 * LD, vt);
    k_attn<<<dim3(21, NH), 512, 0, stream>>>(qh, kh2, vt, ob);
    k_gemm<1><<<dim3(12, 21, 1), 256, 0, stream>>>(ob, wt_all + (size_t)3 * DIM * DIM, bo, bo, bo, d_out);
}

// Round 2
// 200.346 us; speedup vs baseline: 1.0953x; 1.0953x over previous
//
#include <hip/hip_runtime.h>

#define L_SEQ 2688
#define DIM   1536
#define NH    12
#define HD    128
#define BLK_TOK 1344   // 3*H*W
#define HW_   448      // H*W
#define W_    28

typedef unsigned short u16;
typedef unsigned int   u32;
typedef __attribute__((ext_vector_type(4))) float f32x4;
typedef __attribute__((ext_vector_type(8))) short s16x8;

__device__ __forceinline__ u16 f2b(float f) {
    u32 u = __builtin_bit_cast(u32, f);
    return (u16)((u + 0x7FFFu + ((u >> 16) & 1u)) >> 16);   // RNE
}
__device__ __forceinline__ float b2f(u16 b) {
    return __builtin_bit_cast(float, (u32)b << 16);
}

// ---------------------------------------------------------------- x -> bf16
__global__ __launch_bounds__(256) void k_cvt_x(const float* __restrict__ x,
                                               u16* __restrict__ xb, int n4) {
    int i = blockIdx.x * 256 + threadIdx.x;
    int stride = gridDim.x * 256;
    for (; i < n4; i += stride) {
        float4 v = ((const float4*)x)[i];
        ushort4 o;
        o.x = f2b(v.x); o.y = f2b(v.y); o.z = f2b(v.z); o.w = f2b(v.w);
        ((ushort4*)xb)[i] = o;
    }
}

// ------------------------------------- W (f32 [K][N]) -> Wt (bf16 [N][K])
__global__ __launch_bounds__(256) void k_trans_w(const float* __restrict__ w0,
                                                 const float* __restrict__ w1,
                                                 const float* __restrict__ w2,
                                                 const float* __restrict__ w3,
                                                 u16* __restrict__ wt_all) {
    const float* w = blockIdx.z == 0 ? w0 : blockIdx.z == 1 ? w1 : blockIdx.z == 2 ? w2 : w3;
    u16* wt = wt_all + (size_t)blockIdx.z * DIM * DIM;
    __shared__ float t[64][65];
    const int k0 = blockIdx.y * 64, n0 = blockIdx.x * 64;
    const int c = threadIdx.x & 63, rg = threadIdx.x >> 6;
#pragma unroll
    for (int it = 0; it < 16; ++it) {
        int r = rg * 16 + it;
        t[r][c] = w[(size_t)(k0 + r) * DIM + n0 + c];
    }
    __syncthreads();
#pragma unroll
    for (int it = 0; it < 16; ++it) {
        int r = rg * 16 + it;
        wt[(size_t)(n0 + r) * DIM + k0 + c] = f2b(t[c][r]);
    }
}

// ------------------------------------------------- GEMM: C = A*Bt^T + bias
template<int OUTF>
__global__ __launch_bounds__(256, 2) void k_gemm(const u16* __restrict__ A,
                                                 const u16* __restrict__ Bt_all,
                                                 const float* __restrict__ b0,
                                                 const float* __restrict__ b1,
                                                 const float* __restrict__ b2,
                                                 void* __restrict__ out_all) {
    const int z = blockIdx.z;
    const u16* Bt = Bt_all + (size_t)z * DIM * DIM;
    const float* bias = z == 0 ? b0 : z == 1 ? b1 : b2;

    __shared__ u16 lA[128 * 32];
    __shared__ u16 lB[128 * 32];
    const int tid = threadIdx.x, lane = tid & 63, wid = tid >> 6;
    const int wm = wid >> 1, wn = wid & 1;
    const int bm = blockIdx.y, bn = blockIdx.x;
    const int lr = lane & 15, lg = lane >> 4;

    f32x4 acc[4][4] = {};

    for (int kt = 0; kt < DIM / 32; ++kt) {
#pragma unroll
        for (int i = 0; i < 2; ++i) {
            int s = wid * 128 + i * 64 + lane;        // 16B slot id
            int row = s >> 2, c16 = s & 3;            // 4 slots per 32-elem row
            const u16* ga = A + (size_t)(bm * 128 + row) * DIM + kt * 32 + c16 * 8;
            __builtin_amdgcn_global_load_lds(
                (const __attribute__((address_space(1))) u32*)ga,
                (__attribute__((address_space(3))) u32*)&lA[(wid * 128 + i * 64) * 8],
                16, 0, 0);
            const u16* gb = Bt + (size_t)(bn * 128 + row) * DIM + kt * 32 + c16 * 8;
            __builtin_amdgcn_global_load_lds(
                (const __attribute__((address_space(1))) u32*)gb,
                (__attribute__((address_space(3))) u32*)&lB[(wid * 128 + i * 64) * 8],
                16, 0, 0);
        }
        __syncthreads();
        s16x8 af[4], bf[4];
#pragma unroll
        for (int m = 0; m < 4; ++m)
            af[m] = *(const s16x8*)&lA[(wm * 64 + m * 16 + lr) * 32 + lg * 8];
#pragma unroll
        for (int n = 0; n < 4; ++n)
            bf[n] = *(const s16x8*)&lB[(wn * 64 + n * 16 + lr) * 32 + lg * 8];
#pragma unroll
        for (int m = 0; m < 4; ++m)
#pragma unroll
            for (int n = 0; n < 4; ++n)
                acc[m][n] = __builtin_amdgcn_mfma_f32_16x16x32_bf16(af[m], bf[n], acc[m][n], 0, 0, 0);
        __syncthreads();
    }
#pragma unroll
    for (int n = 0; n < 4; ++n) {
        int col = bn * 128 + wn * 64 + n * 16 + lr;
        float bv = bias[col];
#pragma unroll
        for (int m = 0; m < 4; ++m) {
            int row0 = bm * 128 + wm * 64 + m * 16 + lg * 4;
#pragma unroll
            for (int r = 0; r < 4; ++r) {
                float v = acc[m][n][r] + bv;
                if (OUTF)
                    ((float*)out_all)[(size_t)(row0 + r) * DIM + col] = v;
                else
                    ((u16*)out_all)[(size_t)z * L_SEQ * DIM + (size_t)(row0 + r) * DIM + col] = f2b(v);
            }
        }
    }
}

// ---------------- RMSNorm(row of 1536) + RoPE -> [h][i][d]; y selects q/k
__global__ __launch_bounds__(256) void k_norm_rope(const u16* __restrict__ pre_all,
                                                   const float* __restrict__ gq,
                                                   const float* __restrict__ gk,
                                                   const float* __restrict__ freqs,
                                                   u16* __restrict__ qh,
                                                   u16* __restrict__ kh) {
    const int which = blockIdx.y;
    const u16* pre = pre_all + (size_t)which * L_SEQ * DIM;
    const float* g = which ? gk : gq;
    u16* outh = which ? kh : qh;

    const int i = blockIdx.x;
    const int t = threadIdx.x;
    const u32* prow = (const u32*)(pre + (size_t)i * DIM);  // 768 bf16 pairs

    float re[3], im[3];
    float ss = 0.f;
#pragma unroll
    for (int a = 0; a < 3; ++a) {
        u32 p = prow[t + a * 256];
        float x = b2f((u16)(p & 0xFFFFu)), y = b2f((u16)(p >> 16));
        re[a] = x; im[a] = y;
        ss += x * x + y * y;
    }
#pragma unroll
    for (int o = 32; o > 0; o >>= 1) ss += __shfl_down(ss, o, 64);
    __shared__ float sred[4];
    if ((t & 63) == 0) sred[t >> 6] = ss;
    __syncthreads();
    float rms = rsqrtf((sred[0] + sred[1] + sred[2] + sred[3]) * (1.0f / DIM) + 1e-6f);

    const int f = i / HW_;
    const int rem = i - f * HW_;
    const int hp = rem / W_;
    const int wp = rem - hp * W_;
#pragma unroll
    for (int a = 0; a < 3; ++a) {
        int j = t + a * 256;         // pair index in row: head h = j>>6, pj = j&63
        int h = j >> 6, pj = j & 63;
        float2 gg = ((const float2*)g)[j];
        float x = re[a] * rms * gg.x;
        float y = im[a] * rms * gg.y;
        int ridx = pj < 22 ? f : (pj < 43 ? hp : wp);
        float2 cs = ((const float2*)freqs)[ridx * 64 + pj];
        float ore = x * cs.x - y * cs.y;
        float oim = x * cs.y + y * cs.x;
        u32 o = (u32)f2b(ore) | ((u32)f2b(oim) << 16);
        ((u32*)outh)[(size_t)h * (L_SEQ * 64) + (size_t)i * 64 + pj] = o;
    }
}

// ------------------------------------------ v [i][h*128+d] -> vt [h][d][i]
__global__ __launch_bounds__(256) void k_vtrans(const u16* __restrict__ vpre,
                                                u16* __restrict__ vt) {
    const int i0 = blockIdx.x * 64, d0 = blockIdx.y * 64, h = blockIdx.z;
    __shared__ u16 t[64][68];
    const int c = threadIdx.x & 63, rg = threadIdx.x >> 6;
#pragma unroll
    for (int it = 0; it < 16; ++it) {
        int r = rg * 16 + it;
        t[r][c] = vpre[(size_t)(i0 + r) * DIM + h * HD + d0 + c];
    }
    __syncthreads();
#pragma unroll
    for (int it = 0; it < 16; ++it) {
        int r = rg * 16 + it;  // d index
        vt[(size_t)h * (HD * L_SEQ) + (size_t)(d0 + r) * L_SEQ + i0 + c] = t[c][r];
    }
}

// ----------------------------------------------------- flash attention v2
// grid (21, 12). 512 threads = 8 waves; wave owns 16 q-rows. KV tile = 64.
// Double-buffered LDS K/V; async reg-staging; ONE barrier per iteration.
__global__ __launch_bounds__(512, 2) void k_attn(const u16* __restrict__ qh,
                                                 const u16* __restrict__ kh,
                                                 const u16* __restrict__ vt,
                                                 u16* __restrict__ ob) {
    const int qt = blockIdx.x, head = blockIdx.y;
    const int tid = threadIdx.x, lane = tid & 63, wid = tid >> 6;
    const int lr = lane & 15, lg = lane >> 4;
    __shared__ u16 lK[2][64 * 128];   // [j][d], XOR-swizzled
    __shared__ u16 lV[2][128 * 64];   // [d][j], XOR-swizzled
    __shared__ u16 lP[128 * 64];      // [qrow][j], wave-private rows
    const size_t hQ = (size_t)head * ((size_t)L_SEQ * HD);
    const u16* Kbase = kh + hQ;
    const u16* Vbase = vt + (size_t)head * ((size_t)HD * L_SEQ);
    const int qrow0 = qt * 128 + wid * 16;

    // staging slot decomposition (per-thread, 2 x 16B for K and V each)
    const int jk0 = tid >> 4;            // 0..31
    const int ck  = tid & 15;
    const int dv0 = tid >> 3;            // 0..63
    const int cv  = tid & 7;
    const int offK0 = jk0 * 256 + ((ck * 16) ^ ((jk0 & 15) << 4));
    const int offK1 = (32 + jk0) * 256 + ((ck * 16) ^ (((32 + jk0) & 15) << 4));
    const int offV0 = dv0 * 128 + ((cv * 16) ^ ((dv0 & 7) << 4));
    const int offV1 = (64 + dv0) * 128 + ((cv * 16) ^ (((64 + dv0) & 7) << 4));
    const u16* Kg0 = Kbase + (size_t)jk0 * HD + ck * 8;
    const u16* Kg1 = Kg0 + 32 * HD;
    const u16* Vg0 = Vbase + (size_t)dv0 * L_SEQ + cv * 8;
    const u16* Vg1 = Vg0 + (size_t)64 * L_SEQ;

    s16x8 aq[4];
#pragma unroll
    for (int kk = 0; kk < 4; ++kk)
        aq[kk] = *(const s16x8*)&qh[hQ + (size_t)(qrow0 + lr) * HD + kk * 32 + lg * 8];

    f32x4 acc[8] = {};
    float mrun[4], lrun[4];
#pragma unroll
    for (int r = 0; r < 4; ++r) { mrun[r] = -1e30f; lrun[r] = 0.f; }

    const int nt_wave = (qrow0 < BLK_TOK) ? (BLK_TOK / 64) : (L_SEQ / 64);
    const int nt_blk  = (qt * 128 + 127 < BLK_TOK) ? (BLK_TOK / 64) : (L_SEQ / 64);
    const float sc2 = 0.12751739646917983f;  // 1/sqrt(128) * log2(e)

    s16x8 kr0, kr1, vr0, vr1;
    // prologue: issue tile-0 loads
    kr0 = *(const s16x8*)(Kg0);
    kr1 = *(const s16x8*)(Kg1);
    vr0 = *(const s16x8*)(Vg0);
    vr1 = *(const s16x8*)(Vg1);

    for (int t = 0; t < nt_blk; ++t) {
        u16* bK = lK[t & 1];
        u16* bV = lV[t & 1];
        // write staged regs (compiler inserts vmcnt wait)
        *(s16x8*)((char*)bK + offK0) = kr0;
        *(s16x8*)((char*)bK + offK1) = kr1;
        *(s16x8*)((char*)bV + offV0) = vr0;
        *(s16x8*)((char*)bV + offV1) = vr1;
        __syncthreads();
        if (t + 1 < nt_blk) {   // issue next tile's loads; latency hides under compute
            kr0 = *(const s16x8*)(Kg0 + (size_t)(t + 1) * 64 * HD);
            kr1 = *(const s16x8*)(Kg1 + (size_t)(t + 1) * 64 * HD);
            vr0 = *(const s16x8*)(Vg0 + (t + 1) * 64);
            vr1 = *(const s16x8*)(Vg1 + (t + 1) * 64);
        }

        if (t < nt_wave) {
            // S = Q K^T : 16 x 64 for this wave
            f32x4 sv[4] = {};
            __builtin_amdgcn_s_setprio(1);
#pragma unroll
            for (int n = 0; n < 4; ++n) {
                int j = n * 16 + lr;
#pragma unroll
                for (int kk = 0; kk < 4; ++kk) {
                    int off = j * 256 + (((kk * 64 + lg * 16)) ^ ((j & 15) << 4));
                    s16x8 bk = *(const s16x8*)((const char*)bK + off);
                    sv[n] = __builtin_amdgcn_mfma_f32_16x16x32_bf16(aq[kk], bk, sv[n], 0, 0, 0);
                }
            }
            __builtin_amdgcn_s_setprio(0);
            // online softmax (exp2 domain), defer-rescale
            float fac[4];
            int any_r = 0;
#pragma unroll
            for (int r = 0; r < 4; ++r) {
                float v = fmaxf(fmaxf(sv[0][r], sv[1][r]), fmaxf(sv[2][r], sv[3][r]));
                v = fmaxf(v, __shfl_xor(v, 1, 64));
                v = fmaxf(v, __shfl_xor(v, 2, 64));
                v = fmaxf(v, __shfl_xor(v, 4, 64));
                v = fmaxf(v, __shfl_xor(v, 8, 64));
                float mx = v * sc2;
                float mold = mrun[r];
                int resc = (mx - mold) > 11.5f;
                float mm = resc ? mx : mold;
                fac[r] = resc ? __builtin_amdgcn_exp2f(mold - mx) : 1.0f;
                mrun[r] = mm;
                any_r |= resc;
                float sum = 0.f;
#pragma unroll
                for (int n = 0; n < 4; ++n) {
                    float p = __builtin_amdgcn_exp2f(sv[n][r] * sc2 - mm);
                    sv[n][r] = p;
                    sum += p;
                }
                sum += __shfl_xor(sum, 1, 64);
                sum += __shfl_xor(sum, 2, 64);
                sum += __shfl_xor(sum, 4, 64);
                sum += __shfl_xor(sum, 8, 64);
                lrun[r] = lrun[r] * fac[r] + sum;
            }
            if (__any(any_r)) {
#pragma unroll
                for (int nd = 0; nd < 8; ++nd)
#pragma unroll
                    for (int r = 0; r < 4; ++r) acc[nd][r] *= fac[r];
            }
            // P -> LDS (bf16, swizzled); wave-private rows so no barrier needed
#pragma unroll
            for (int n = 0; n < 4; ++n)
#pragma unroll
                for (int r = 0; r < 4; ++r) {
                    int rowl = wid * 16 + lg * 4 + r;
                    int jb = (n * 16 + lr) * 2;
                    *(u16*)((char*)lP + rowl * 128 + (jb ^ ((rowl & 7) << 4))) = f2b(sv[n][r]);
                }
            // O += P V
            __builtin_amdgcn_s_setprio(1);
#pragma unroll
            for (int kk2 = 0; kk2 < 2; ++kk2) {
                int rowl = wid * 16 + lr;
                int jb = kk2 * 64 + lg * 16;
                s16x8 pa = *(const s16x8*)((const char*)lP + rowl * 128 + (jb ^ ((rowl & 7) << 4)));
#pragma unroll
                for (int nd = 0; nd < 8; ++nd) {
                    int d = nd * 16 + lr;
                    s16x8 bv = *(const s16x8*)((const char*)bV + d * 128 + (jb ^ ((d & 7) << 4)));
                    acc[nd] = __builtin_amdgcn_mfma_f32_16x16x32_bf16(pa, bv, acc[nd], 0, 0, 0);
                }
            }
            __builtin_amdgcn_s_setprio(0);
        }
        // NOTE: single barrier per iteration (top of loop) is sufficient with
        // double-buffered K/V: write(t+2,buf) is separated from read(t,buf)
        // by the barrier at t+1.
    }
    // normalize + write bf16 [L][DIM]
#pragma unroll
    for (int r = 0; r < 4; ++r) {
        float inv = 1.0f / lrun[r];
        int row = qrow0 + lg * 4 + r;
#pragma unroll
        for (int nd = 0; nd < 8; ++nd) {
            int col = head * HD + nd * 16 + lr;
            ob[(size_t)row * DIM + col] = f2b(acc[nd][r] * inv);
        }
    }
}

// ---------------------------------------------------------------- launcher
extern "C" void kernel_launch(void* const* d_in, const int* in_sizes, int n_in,
                              void* d_out, int out_size, void* d_ws, size_t ws_size,
                              hipStream_t stream) {
    const float* x     = (const float*)d_in[0];
    const float* freqs = (const float*)d_in[3];
    const float* Wq    = (const float*)d_in[4];
    const float* bq    = (const float*)d_in[5];
    const float* Wk    = (const float*)d_in[6];
    const float* bk    = (const float*)d_in[7];
    const float* Wv    = (const float*)d_in[8];
    const float* bv    = (const float*)d_in[9];
    const float* Wo    = (const float*)d_in[10];
    const float* bo    = (const float*)d_in[11];
    const float* gq    = (const float*)d_in[12];
    const float* gk    = (const float*)d_in[13];

    const size_t LD = (size_t)L_SEQ * DIM;   // elements
    u16* wt_all  = (u16*)d_ws;                         // 4 * DIM*DIM bf16
    u16* xb      = wt_all + (size_t)4 * DIM * DIM;     // L*DIM
    u16* pre_all = xb + LD;                            // 3 * L*DIM (q,k,v pre)
    u16* qh      = pre_all + 3 * LD;                   // [h][i][d]
    u16* kh2     = qh + LD;
    u16* vt      = kh2 + LD;
    u16* ob      = vt + LD;                            // attn out bf16 [i][c]

    k_cvt_x<<<2016, 256, 0, stream>>>(x, xb, (int)(LD / 4));
    k_trans_w<<<dim3(24, 24, 4), 256, 0, stream>>>(Wq, Wk, Wv, Wo, wt_all);
    k_gemm<0><<<dim3(12, 21, 3), 256, 0, stream>>>(xb, wt_all, bq, bk, bv, pre_all);
    k_norm_rope<<<dim3(L_SEQ, 2), 256, 0, stream>>>(pre_all, gq, gk, freqs, qh, kh2);
    k_vtrans<<<dim3(42, 2, NH), 256, 0, stream>>>(pre_all + 2 * LD, vt);
    k_attn<<<dim3(21, NH), 512, 0, stream>>>(qh, kh2, vt, ob);
    k_gemm<1><<<dim3(12, 21, 1), 256, 0, stream>>>(ob, wt_all + (size_t)3 * DIM * DIM, bo, bo, bo, d_out);
}

// Round 3
// 188.755 us; speedup vs baseline: 1.1626x; 1.0614x over previous
//
#include <hip/hip_runtime.h>

#define L_SEQ 2688
#define DIM   1536
#define NH    12
#define HD    128
#define BLK_TOK 1344   // 3*H*W
#define HW_   448      // H*W
#define W_    28

typedef unsigned short u16;
typedef unsigned int   u32;
typedef __attribute__((ext_vector_type(4))) float f32x4;
typedef __attribute__((ext_vector_type(8))) short s16x8;

__device__ __forceinline__ u16 f2b(float f) {
    u32 u = __builtin_bit_cast(u32, f);
    return (u16)((u + 0x7FFFu + ((u >> 16) & 1u)) >> 16);   // RNE
}
__device__ __forceinline__ float b2f(u16 b) {
    return __builtin_bit_cast(float, (u32)b << 16);
}

// ---------------------------------------------------------------- x -> bf16
__global__ __launch_bounds__(256) void k_cvt_x(const float* __restrict__ x,
                                               u16* __restrict__ xb, int n4) {
    int i = blockIdx.x * 256 + threadIdx.x;
    int stride = gridDim.x * 256;
    for (; i < n4; i += stride) {
        float4 v = ((const float4*)x)[i];
        ushort4 o;
        o.x = f2b(v.x); o.y = f2b(v.y); o.z = f2b(v.z); o.w = f2b(v.w);
        ((ushort4*)xb)[i] = o;
    }
}

// ------------------------------------- W (f32 [K][N]) -> Wt (bf16 [N][K])
__global__ __launch_bounds__(256) void k_trans_w(const float* __restrict__ w0,
                                                 const float* __restrict__ w1,
                                                 const float* __restrict__ w2,
                                                 const float* __restrict__ w3,
                                                 u16* __restrict__ wt_all) {
    const float* w = blockIdx.z == 0 ? w0 : blockIdx.z == 1 ? w1 : blockIdx.z == 2 ? w2 : w3;
    u16* wt = wt_all + (size_t)blockIdx.z * DIM * DIM;
    __shared__ float t[64][65];
    const int k0 = blockIdx.y * 64, n0 = blockIdx.x * 64;
    const int c = threadIdx.x & 63, rg = threadIdx.x >> 6;
#pragma unroll
    for (int it = 0; it < 16; ++it) {
        int r = rg * 16 + it;
        t[r][c] = w[(size_t)(k0 + r) * DIM + n0 + c];
    }
    __syncthreads();
#pragma unroll
    for (int it = 0; it < 16; ++it) {
        int r = rg * 16 + it;
        wt[(size_t)(n0 + r) * DIM + k0 + c] = f2b(t[c][r]);
    }
}

// ------------------------------------------------- GEMM: C = A*Bt^T + bias
template<int OUTF>
__global__ __launch_bounds__(256, 2) void k_gemm(const u16* __restrict__ A,
                                                 const u16* __restrict__ Bt_all,
                                                 const float* __restrict__ b0,
                                                 const float* __restrict__ b1,
                                                 const float* __restrict__ b2,
                                                 void* __restrict__ out_all) {
    const int z = blockIdx.z;
    const u16* Bt = Bt_all + (size_t)z * DIM * DIM;
    const float* bias = z == 0 ? b0 : z == 1 ? b1 : b2;

    __shared__ u16 lA[128 * 32];
    __shared__ u16 lB[128 * 32];
    const int tid = threadIdx.x, lane = tid & 63, wid = tid >> 6;
    const int wm = wid >> 1, wn = wid & 1;
    const int bm = blockIdx.y, bn = blockIdx.x;
    const int lr = lane & 15, lg = lane >> 4;

    f32x4 acc[4][4] = {};

    for (int kt = 0; kt < DIM / 32; ++kt) {
#pragma unroll
        for (int i = 0; i < 2; ++i) {
            int s = wid * 128 + i * 64 + lane;        // 16B slot id
            int row = s >> 2, c16 = s & 3;            // 4 slots per 32-elem row
            const u16* ga = A + (size_t)(bm * 128 + row) * DIM + kt * 32 + c16 * 8;
            __builtin_amdgcn_global_load_lds(
                (const __attribute__((address_space(1))) u32*)ga,
                (__attribute__((address_space(3))) u32*)&lA[(wid * 128 + i * 64) * 8],
                16, 0, 0);
            const u16* gb = Bt + (size_t)(bn * 128 + row) * DIM + kt * 32 + c16 * 8;
            __builtin_amdgcn_global_load_lds(
                (const __attribute__((address_space(1))) u32*)gb,
                (__attribute__((address_space(3))) u32*)&lB[(wid * 128 + i * 64) * 8],
                16, 0, 0);
        }
        __syncthreads();
        s16x8 af[4], bf[4];
#pragma unroll
        for (int m = 0; m < 4; ++m)
            af[m] = *(const s16x8*)&lA[(wm * 64 + m * 16 + lr) * 32 + lg * 8];
#pragma unroll
        for (int n = 0; n < 4; ++n)
            bf[n] = *(const s16x8*)&lB[(wn * 64 + n * 16 + lr) * 32 + lg * 8];
#pragma unroll
        for (int m = 0; m < 4; ++m)
#pragma unroll
            for (int n = 0; n < 4; ++n)
                acc[m][n] = __builtin_amdgcn_mfma_f32_16x16x32_bf16(af[m], bf[n], acc[m][n], 0, 0, 0);
        __syncthreads();
    }
#pragma unroll
    for (int n = 0; n < 4; ++n) {
        int col = bn * 128 + wn * 64 + n * 16 + lr;
        float bv = bias[col];
#pragma unroll
        for (int m = 0; m < 4; ++m) {
            int row0 = bm * 128 + wm * 64 + m * 16 + lg * 4;
#pragma unroll
            for (int r = 0; r < 4; ++r) {
                float v = acc[m][n][r] + bv;
                if (OUTF)
                    ((float*)out_all)[(size_t)(row0 + r) * DIM + col] = v;
                else
                    ((u16*)out_all)[(size_t)z * L_SEQ * DIM + (size_t)(row0 + r) * DIM + col] = f2b(v);
            }
        }
    }
}

// ---------------- RMSNorm(row of 1536) + RoPE -> [h][i][d]; y selects q/k
__global__ __launch_bounds__(256) void k_norm_rope(const u16* __restrict__ pre_all,
                                                   const float* __restrict__ gq,
                                                   const float* __restrict__ gk,
                                                   const float* __restrict__ freqs,
                                                   u16* __restrict__ qh,
                                                   u16* __restrict__ kh) {
    const int which = blockIdx.y;
    const u16* pre = pre_all + (size_t)which * L_SEQ * DIM;
    const float* g = which ? gk : gq;
    u16* outh = which ? kh : qh;

    const int i = blockIdx.x;
    const int t = threadIdx.x;
    const u32* prow = (const u32*)(pre + (size_t)i * DIM);  // 768 bf16 pairs

    float re[3], im[3];
    float ss = 0.f;
#pragma unroll
    for (int a = 0; a < 3; ++a) {
        u32 p = prow[t + a * 256];
        float x = b2f((u16)(p & 0xFFFFu)), y = b2f((u16)(p >> 16));
        re[a] = x; im[a] = y;
        ss += x * x + y * y;
    }
#pragma unroll
    for (int o = 32; o > 0; o >>= 1) ss += __shfl_down(ss, o, 64);
    __shared__ float sred[4];
    if ((t & 63) == 0) sred[t >> 6] = ss;
    __syncthreads();
    float rms = rsqrtf((sred[0] + sred[1] + sred[2] + sred[3]) * (1.0f / DIM) + 1e-6f);

    const int f = i / HW_;
    const int rem = i - f * HW_;
    const int hp = rem / W_;
    const int wp = rem - hp * W_;
#pragma unroll
    for (int a = 0; a < 3; ++a) {
        int j = t + a * 256;         // pair index in row: head h = j>>6, pj = j&63
        int h = j >> 6, pj = j & 63;
        float2 gg = ((const float2*)g)[j];
        float x = re[a] * rms * gg.x;
        float y = im[a] * rms * gg.y;
        int ridx = pj < 22 ? f : (pj < 43 ? hp : wp);
        float2 cs = ((const float2*)freqs)[ridx * 64 + pj];
        float ore = x * cs.x - y * cs.y;
        float oim = x * cs.y + y * cs.x;
        u32 o = (u32)f2b(ore) | ((u32)f2b(oim) << 16);
        ((u32*)outh)[(size_t)h * (L_SEQ * 64) + (size_t)i * 64 + pj] = o;
    }
}

// ------------------------------------------ v [i][h*128+d] -> vt [h][d][i]
__global__ __launch_bounds__(256) void k_vtrans(const u16* __restrict__ vpre,
                                                u16* __restrict__ vt) {
    const int i0 = blockIdx.x * 64, d0 = blockIdx.y * 64, h = blockIdx.z;
    __shared__ u16 t[64][68];
    const int c = threadIdx.x & 63, rg = threadIdx.x >> 6;
#pragma unroll
    for (int it = 0; it < 16; ++it) {
        int r = rg * 16 + it;
        t[r][c] = vpre[(size_t)(i0 + r) * DIM + h * HD + d0 + c];
    }
    __syncthreads();
#pragma unroll
    for (int it = 0; it < 16; ++it) {
        int r = rg * 16 + it;  // d index
        vt[(size_t)h * (HD * L_SEQ) + (size_t)(d0 + r) * L_SEQ + i0 + c] = t[c][r];
    }
}

// ----------------------------------------------------- flash attention v3
// 756 blocks x 256 thr (4 waves, 16 q-rows/wave). Uniform 21 KV tiles/block.
// Swapped QK^T (lane owns a q-row), gload_lds staging w/ pre-swizzled source,
// split-KV for second block-half with f32 partials + LSE merge.
__global__ __launch_bounds__(256, 2) void k_attn(const u16* __restrict__ qh,
                                                 const u16* __restrict__ kh,
                                                 const u16* __restrict__ vt,
                                                 u16* __restrict__ ob,
                                                 float* __restrict__ Opart,
                                                 float* __restrict__ mlp) {
    __shared__ u16 lK[2][64 * 128];   // [j][d], slot-XOR swizzled, dbuf
    __shared__ u16 lV[2][128 * 64];   // [d][j], slot-XOR swizzled, dbuf
    __shared__ u16 lP[64 * 64];       // [qrow][j], wave-private rows

    // bijective XCD swizzle: 756 = 8*94 + 4 (head-major work list per XCD)
    const int flat = blockIdx.x;
    const int xcd = flat & 7, idx = flat >> 3;
    const int work = (xcd < 4) ? (xcd * 95 + idx) : (380 + (xcd - 4) * 94 + idx);
    const int head = work / 63;
    const int bx = work - head * 63;
    int qt, kv0, mode;
    if (bx < 21)      { qt = bx;      kv0 = 0;  mode = 0; }
    else if (bx < 42) { qt = bx;      kv0 = 0;  mode = 1; }
    else              { qt = bx - 21; kv0 = 21; mode = 2; }

    const int tid = threadIdx.x, lane = tid & 63, wid = tid >> 6;
    const int lr = lane & 15, lg = lane >> 4;
    const size_t hOff = (size_t)head * ((size_t)L_SEQ * HD);
    const u16* Kh = kh + hOff;
    const u16* Vh = vt + hOff;
    const int qrow0 = qt * 64 + wid * 16;

    // Q fragments (B-operand): Q[qrow0+lr][32kk + 8lg ..]
    s16x8 aq[4];
#pragma unroll
    for (int kk = 0; kk < 4; ++kk)
        aq[kk] = *(const s16x8*)&qh[hOff + (size_t)(qrow0 + lr) * HD + kk * 32 + lg * 8];

    // staging: pre-swizzled global sources, linear LDS dest (gload_lds)
    const u16* kap[4]; const u16* vap[4];
    int ldsb[4];
#pragma unroll
    for (int i = 0; i < 4; ++i) {
        int jrow = wid * 16 + i * 4 + lg;
        kap[i] = Kh + (size_t)(kv0 * 64 + jrow) * HD + 8 * ((lane & 15) ^ (i * 4 + lg));
        int drow = wid * 32 + i * 8 + (lane >> 3);
        vap[i] = Vh + (size_t)drow * L_SEQ + kv0 * 64 + 8 * ((lane & 7) ^ ((lane >> 3) & 7));
        ldsb[i] = wid * 4096 + i * 1024;   // bytes
    }
#define STAGE(T, BUF)                                                              \
    {                                                                              \
        _Pragma("unroll")                                                          \
        for (int i = 0; i < 4; ++i)                                                \
            __builtin_amdgcn_global_load_lds(                                      \
                (const __attribute__((address_space(1))) u32*)(kap[i] + (size_t)(T) * 8192), \
                (__attribute__((address_space(3))) u32*)((char*)&lK[BUF][0] + ldsb[i]), 16, 0, 0); \
        _Pragma("unroll")                                                          \
        for (int i = 0; i < 4; ++i)                                                \
            __builtin_amdgcn_global_load_lds(                                      \
                (const __attribute__((address_space(1))) u32*)(vap[i] + (T) * 64), \
                (__attribute__((address_space(3))) u32*)((char*)&lV[BUF][0] + ldsb[i]), 16, 0, 0); \
    }

    f32x4 acc[8] = {};
    float mrun = -1e30f, lrun = 0.f;
    const float sc2 = 0.12751739646917983f;  // 1/sqrt(128) * log2(e)
    const int prow = wid * 16 + lr;
    const int pswz = (lr & 7) << 4;

    STAGE(0, 0);
    for (int t = 0; t < 21; ++t) {
        __syncthreads();                 // drains gload_lds for tile t
        if (t < 20) STAGE(t + 1, (t + 1) & 1);
        const u16* bK = lK[t & 1];
        const u16* bV = lV[t & 1];

        // S^T = K Q^T  (lane holds S[q=lr][j=16n+4lg+r])
        f32x4 sv[4] = {};
        __builtin_amdgcn_s_setprio(1);
#pragma unroll
        for (int n = 0; n < 4; ++n) {
#pragma unroll
            for (int kk = 0; kk < 4; ++kk) {
                int off = (16 * n + lr) * 256 + ((64 * kk + 16 * lg) ^ (lr << 4));
                s16x8 kf = *(const s16x8*)((const char*)bK + off);
                sv[n] = __builtin_amdgcn_mfma_f32_16x16x32_bf16(kf, aq[kk], sv[n], 0, 0, 0);
            }
        }
        __builtin_amdgcn_s_setprio(0);

        // online softmax, row-local (2 shuffles per reduce)
        float mx = sv[0][0];
#pragma unroll
        for (int n = 0; n < 4; ++n) {
            mx = fmaxf(mx, fmaxf(fmaxf(sv[n][0], sv[n][1]), fmaxf(sv[n][2], sv[n][3])));
        }
        mx = fmaxf(mx, __shfl_xor(mx, 16, 64));
        mx = fmaxf(mx, __shfl_xor(mx, 32, 64));
        mx *= sc2;
        const int resc = (mx - mrun) > 11.5f;
        const float mm = resc ? mx : mrun;
        const float fac = resc ? __builtin_amdgcn_exp2f(mrun - mm) : 1.0f;
        mrun = mm;
        float p[4][4];
        float sum = 0.f;
#pragma unroll
        for (int n = 0; n < 4; ++n)
#pragma unroll
            for (int r = 0; r < 4; ++r) {
                float pv = __builtin_amdgcn_exp2f(sv[n][r] * sc2 - mm);
                p[n][r] = pv;
                sum += pv;
            }
        sum += __shfl_xor(sum, 16, 64);
        sum += __shfl_xor(sum, 32, 64);
        lrun = lrun * fac + sum;
        if (__any(resc)) {
#pragma unroll
            for (int r = 0; r < 4; ++r) {
                float fr = __shfl(fac, 4 * lg + r, 64);
#pragma unroll
                for (int nd = 0; nd < 8; ++nd) acc[nd][r] *= fr;
            }
        }

        // P -> LDS: 4 consecutive j per lane -> one b64 write per n
#pragma unroll
        for (int n = 0; n < 4; ++n) {
            u32 lo = (u32)f2b(p[n][0]) | ((u32)f2b(p[n][1]) << 16);
            u32 hi = (u32)f2b(p[n][2]) | ((u32)f2b(p[n][3]) << 16);
            uint2 wpk; wpk.x = lo; wpk.y = hi;
            int addr = prow * 128 + ((32 * n + 8 * lg) ^ pswz);
            *(uint2*)((char*)lP + addr) = wpk;
        }

        // O += P V
        __builtin_amdgcn_s_setprio(1);
#pragma unroll
        for (int kk2 = 0; kk2 < 2; ++kk2) {
            int pa_off = prow * 128 + ((64 * kk2 + 16 * lg) ^ pswz);
            s16x8 pa = *(const s16x8*)((const char*)lP + pa_off);
#pragma unroll
            for (int nd = 0; nd < 8; ++nd) {
                int va = (16 * nd + lr) * 128 + ((64 * kk2 + 16 * lg) ^ ((lr & 7) << 4));
                s16x8 bvv = *(const s16x8*)((const char*)bV + va);
                acc[nd] = __builtin_amdgcn_mfma_f32_16x16x32_bf16(pa, bvv, acc[nd], 0, 0, 0);
            }
        }
        __builtin_amdgcn_s_setprio(0);
    }

    if (mode == 0) {
        // normalize + write bf16; l for acc-row q=4lg+r lives at lane 4lg+r
#pragma unroll
        for (int r = 0; r < 4; ++r) {
            float invl = 1.0f / __shfl(lrun, 4 * lg + r, 64);
            int row = qrow0 + 4 * lg + r;
#pragma unroll
            for (int nd = 0; nd < 8; ++nd)
                ob[(size_t)row * DIM + head * HD + nd * 16 + lr] = f2b(acc[nd][r] * invl);
        }
    } else {
        const int pair = (head * 21 + (qt - 21)) * 2 + (mode - 1);
        float* Op = Opart + (size_t)pair * (64 * 128);
#pragma unroll
        for (int r = 0; r < 4; ++r) {
            int rowl = wid * 16 + 4 * lg + r;
#pragma unroll
            for (int nd = 0; nd < 8; ++nd)
                Op[rowl * 128 + nd * 16 + lr] = acc[nd][r];
        }
        if (lg == 0) {
            float2 ml; ml.x = mrun; ml.y = lrun;
            ((float2*)mlp)[(size_t)pair * 64 + wid * 16 + lr] = ml;
        }
    }
#undef STAGE
}

// ------------------------------------------------- LSE merge of 2 partials
__global__ __launch_bounds__(256) void k_merge(const float* __restrict__ Opart,
                                               const float* __restrict__ mlp,
                                               u16* __restrict__ ob) {
    const int b = blockIdx.x;
    const int qt2 = b % 21, head = b / 21;
    const int pair = head * 21 + qt2;
    const float* O0 = Opart + (size_t)pair * 2 * 8192;
    const float* O1 = O0 + 8192;
    const int tid = threadIdx.x;
    const int row = tid >> 2, cs = (tid & 3) * 32;
    float2 a = ((const float2*)mlp)[(size_t)pair * 2 * 64 + row];
    float2 c = ((const float2*)mlp)[(size_t)(pair * 2 + 1) * 64 + row];
    float M = fmaxf(a.x, c.x);
    float w0 = exp2f(a.x - M), w1 = exp2f(c.x - M);
    float inv = 1.0f / (w0 * a.y + w1 * c.y);
    w0 *= inv; w1 *= inv;
    const int rowg = BLK_TOK + qt2 * 64 + row;
    u32* orow = (u32*)(ob + (size_t)rowg * DIM + head * HD + cs);
    const float4* p0 = (const float4*)(O0 + row * 128 + cs);
    const float4* p1 = (const float4*)(O1 + row * 128 + cs);
#pragma unroll
    for (int u = 0; u < 8; ++u) {
        float4 x0 = p0[u], x1 = p1[u];
        float o0 = x0.x * w0 + x1.x * w1;
        float o1 = x0.y * w0 + x1.y * w1;
        float o2 = x0.z * w0 + x1.z * w1;
        float o3 = x0.w * w0 + x1.w * w1;
        orow[u * 2]     = (u32)f2b(o0) | ((u32)f2b(o1) << 16);
        orow[u * 2 + 1] = (u32)f2b(o2) | ((u32)f2b(o3) << 16);
    }
}

// ---------------------------------------------------------------- launcher
extern "C" void kernel_launch(void* const* d_in, const int* in_sizes, int n_in,
                              void* d_out, int out_size, void* d_ws, size_t ws_size,
                              hipStream_t stream) {
    const float* x     = (const float*)d_in[0];
    const float* freqs = (const float*)d_in[3];
    const float* Wq    = (const float*)d_in[4];
    const float* bq    = (const float*)d_in[5];
    const float* Wk    = (const float*)d_in[6];
    const float* bk    = (const float*)d_in[7];
    const float* Wv    = (const float*)d_in[8];
    const float* bv    = (const float*)d_in[9];
    const float* Wo    = (const float*)d_in[10];
    const float* bo    = (const float*)d_in[11];
    const float* gq    = (const float*)d_in[12];
    const float* gk    = (const float*)d_in[13];

    const size_t LD = (size_t)L_SEQ * DIM;   // elements
    u16* wt_all  = (u16*)d_ws;                         // 4 * DIM*DIM bf16
    u16* xb      = wt_all + (size_t)4 * DIM * DIM;     // L*DIM
    u16* pre_all = xb + LD;                            // 3 * L*DIM (q,k,v pre)
    u16* qh      = pre_all + 3 * LD;                   // [h][i][d]
    u16* kh2     = qh + LD;
    u16* vt      = kh2 + LD;
    u16* ob      = vt + LD;                            // attn out bf16 [i][c]
    // partials alias pre_all (dead once attention starts): 16.8 MB < 24.8 MB
    float* Opart = (float*)pre_all;                    // 12*21*2*64*128 f32
    float* mlp   = Opart + (size_t)12 * 21 * 2 * 64 * 128;

    k_cvt_x<<<2016, 256, 0, stream>>>(x, xb, (int)(LD / 4));
    k_trans_w<<<dim3(24, 24, 4), 256, 0, stream>>>(Wq, Wk, Wv, Wo, wt_all);
    k_gemm<0><<<dim3(12, 21, 3), 256, 0, stream>>>(xb, wt_all, bq, bk, bv, pre_all);
    k_norm_rope<<<dim3(L_SEQ, 2), 256, 0, stream>>>(pre_all, gq, gk, freqs, qh, kh2);
    k_vtrans<<<dim3(42, 2, NH), 256, 0, stream>>>(pre_all + 2 * LD, vt);
    k_attn<<<dim3(756), 256, 0, stream>>>(qh, kh2, vt, ob, Opart, mlp);
    k_merge<<<dim3(252), 256, 0, stream>>>(Opart, mlp, ob);
    k_gemm<1><<<dim3(12, 21, 1), 256, 0, stream>>>(ob, wt_all + (size_t)3 * DIM * DIM, bo, bo, bo, d_out);
}